// Round 9
// baseline (817.303 us; speedup 1.0000x reference)
//
#include <hip/hip_runtime.h>
#include <cstdint>
#include <cstddef>

// Problem constants
#define BB   8
#define TT   4096
#define DD   512
#define UU   512
#define NN   1536   // 3*UU
#define KK   1024   // 2*DD
#define MM   32768  // BB*TT
#define NCH2 128    // fused-scan chunks
#define CHL2 32     // fused-scan chunk length (NCH2*CHL2 == TT)

using bf16x8 = __attribute__((ext_vector_type(8))) __bf16;
using f32x4  = __attribute__((ext_vector_type(4))) float;

__device__ __forceinline__ unsigned short f2bf(float f) {
    unsigned u = __float_as_uint(f);
    u += 0x7fffu + ((u >> 16) & 1u);   // RTNE
    return (unsigned short)(u >> 16);
}
__device__ __forceinline__ float bf2f(unsigned short s) {
    return __uint_as_float(((unsigned)s) << 16);
}
// fast activations: v_rcp instead of IEEE divide (error ~1ulp << bf16 rounding)
__device__ __forceinline__ float sigf(float x) {
    return __builtin_amdgcn_rcpf(1.0f + __expf(-x));
}
__device__ __forceinline__ float tanh_(float x) {
    return 1.0f - 2.0f * __builtin_amdgcn_rcpf(1.0f + __expf(2.0f * x));
}

__device__ __forceinline__ void async16(const void* g, void* l) {
    __builtin_amdgcn_global_load_lds(
        (__attribute__((address_space(1))) void*)g,
        (__attribute__((address_space(3))) void*)l, 16, 0, 0);
}

// ---- 1) prep: pad+convert x -> xpad (bf16), and transpose kernel -> kT ----
__global__ void k_prep(const float* __restrict__ x, unsigned short* __restrict__ xpad,
                       const float* __restrict__ kern, unsigned short* __restrict__ kT) {
    int bx = blockIdx.x;
    int by = blockIdx.y;
    int tid = threadIdx.x;
    if (bx < 2049) {
        int q = bx * 256 + tid;              // quad index within batch
        if (q >= 4097 * 128) return;
        int tp = q >> 7;                     // 0..4096
        int d  = (q & 127) << 2;             // 0..508
        size_t oi = ((size_t)by * 4097 + tp) * 512 + d;
        ushort4 o;
        if (tp == 0) {
            o.x = o.y = o.z = o.w = 0;
        } else {
            float4 v = *(const float4*)(x + ((size_t)by * 4096 + (tp - 1)) * 512 + d);
            o.x = f2bf(v.x); o.y = f2bf(v.y); o.z = f2bf(v.z); o.w = f2bf(v.w);
        }
        *(ushort4*)(xpad + oi) = o;
    } else {
        __shared__ float tile[32][33];
        int idx = (bx - 2049) * 8 + by;      // 0..191
        int c  = tid & 31;
        int r0 = tid >> 5;                   // 0..7
        for (int t8 = 0; t8 < 8; ++t8) {
            int tnum = idx * 8 + t8;         // 0..1535
            int k0 = (tnum & 31) * 32;       // 32 K-tiles
            int n0 = (tnum >> 5) * 32;       // 48 N-tiles
#pragma unroll
            for (int rr = r0; rr < 32; rr += 8)
                tile[rr][c] = kern[(size_t)(k0 + rr) * NN + n0 + c];
            __syncthreads();
#pragma unroll
            for (int rr = r0; rr < 32; rr += 8)
                kT[(size_t)(n0 + rr) * KK + k0 + c] = f2bf(tile[c][rr]);
            __syncthreads();
        }
    }
}

// ---- 2) GEMM: 256x256 tile, BK=64, 8 waves (2Mx4N), 8-phase READ-AHEAD pipeline ----
// (round-4 kernel, best measured)

#define STAGE_A(BUF, KT, KH) do { \
    async16(xpad + abase + (size_t)rowS0 * 512 + ((KT) * 64 + (KH) * 32 + kcS0), \
            smem + (BUF) * 65536 + (KH) * 16384 + offL0); \
    async16(xpad + abase + (size_t)rowS1 * 512 + ((KT) * 64 + (KH) * 32 + kcS1), \
            smem + (BUF) * 65536 + (KH) * 16384 + offL1); \
} while (0)

#define STAGE_B(BUF, KT, KH) do { \
    async16(kTg + (size_t)(n0 + rowS0) * 1024 + ((KT) * 64 + (KH) * 32 + kcS0), \
            smem + (BUF) * 65536 + 32768 + (KH) * 16384 + offL0); \
    async16(kTg + (size_t)(n0 + rowS1) * 1024 + ((KT) * 64 + (KH) * 32 + kcS1), \
            smem + (BUF) * 65536 + 32768 + (KH) * 16384 + offL1); \
} while (0)

#define VM4 asm volatile("s_waitcnt vmcnt(4)" ::: "memory")
#define VM2 asm volatile("s_waitcnt vmcnt(2)" ::: "memory")
#define VM0 asm volatile("s_waitcnt vmcnt(0)" ::: "memory")

#define LDS_A(BUF, KS, MR) (*(const bf16x8*)(smem + (BUF) * 65536 + (KS) * 16384 + (MR) * 1024 + ldsA))
#define LDS_B(BUF, KS, NR) (*(const bf16x8*)(smem + (BUF) * 65536 + (KS) * 16384 + (NR) * 1024 + ldsB))

#define PH(DO_R, RBUF, RKS, RMH, AFN, LBN, BFN, AFC, BFC, MH, STG, VMW) \
    __builtin_amdgcn_s_barrier(); \
    if (DO_R) { \
        AFN[0] = LDS_A(RBUF, RKS, (RMH) * 4 + 0); \
        AFN[1] = LDS_A(RBUF, RKS, (RMH) * 4 + 1); \
        AFN[2] = LDS_A(RBUF, RKS, (RMH) * 4 + 2); \
        AFN[3] = LDS_A(RBUF, RKS, (RMH) * 4 + 3); \
        if (LBN) { \
            BFN[0] = LDS_B(RBUF, RKS, 0); \
            BFN[1] = LDS_B(RBUF, RKS, 1); \
            BFN[2] = LDS_B(RBUF, RKS, 2); \
            BFN[3] = LDS_B(RBUF, RKS, 3); \
        } \
    } \
    STG; \
    __builtin_amdgcn_sched_barrier(0); \
    __builtin_amdgcn_s_setprio(1); \
    acc[(MH)*4+0][0] = __builtin_amdgcn_mfma_f32_16x16x32_bf16(AFC[0], BFC[0], acc[(MH)*4+0][0], 0, 0, 0); \
    acc[(MH)*4+0][1] = __builtin_amdgcn_mfma_f32_16x16x32_bf16(AFC[0], BFC[1], acc[(MH)*4+0][1], 0, 0, 0); \
    acc[(MH)*4+0][2] = __builtin_amdgcn_mfma_f32_16x16x32_bf16(AFC[0], BFC[2], acc[(MH)*4+0][2], 0, 0, 0); \
    acc[(MH)*4+0][3] = __builtin_amdgcn_mfma_f32_16x16x32_bf16(AFC[0], BFC[3], acc[(MH)*4+0][3], 0, 0, 0); \
    acc[(MH)*4+1][0] = __builtin_amdgcn_mfma_f32_16x16x32_bf16(AFC[1], BFC[0], acc[(MH)*4+1][0], 0, 0, 0); \
    acc[(MH)*4+1][1] = __builtin_amdgcn_mfma_f32_16x16x32_bf16(AFC[1], BFC[1], acc[(MH)*4+1][1], 0, 0, 0); \
    acc[(MH)*4+1][2] = __builtin_amdgcn_mfma_f32_16x16x32_bf16(AFC[1], BFC[2], acc[(MH)*4+1][2], 0, 0, 0); \
    acc[(MH)*4+1][3] = __builtin_amdgcn_mfma_f32_16x16x32_bf16(AFC[1], BFC[3], acc[(MH)*4+1][3], 0, 0, 0); \
    acc[(MH)*4+2][0] = __builtin_amdgcn_mfma_f32_16x16x32_bf16(AFC[2], BFC[0], acc[(MH)*4+2][0], 0, 0, 0); \
    acc[(MH)*4+2][1] = __builtin_amdgcn_mfma_f32_16x16x32_bf16(AFC[2], BFC[1], acc[(MH)*4+2][1], 0, 0, 0); \
    acc[(MH)*4+2][2] = __builtin_amdgcn_mfma_f32_16x16x32_bf16(AFC[2], BFC[2], acc[(MH)*4+2][2], 0, 0, 0); \
    acc[(MH)*4+2][3] = __builtin_amdgcn_mfma_f32_16x16x32_bf16(AFC[2], BFC[3], acc[(MH)*4+2][3], 0, 0, 0); \
    acc[(MH)*4+3][0] = __builtin_amdgcn_mfma_f32_16x16x32_bf16(AFC[3], BFC[0], acc[(MH)*4+3][0], 0, 0, 0); \
    acc[(MH)*4+3][1] = __builtin_amdgcn_mfma_f32_16x16x32_bf16(AFC[3], BFC[1], acc[(MH)*4+3][1], 0, 0, 0); \
    acc[(MH)*4+3][2] = __builtin_amdgcn_mfma_f32_16x16x32_bf16(AFC[3], BFC[2], acc[(MH)*4+3][2], 0, 0, 0); \
    acc[(MH)*4+3][3] = __builtin_amdgcn_mfma_f32_16x16x32_bf16(AFC[3], BFC[3], acc[(MH)*4+3][3], 0, 0, 0); \
    __builtin_amdgcn_s_setprio(0); \
    VMW;

__global__ __launch_bounds__(512, 2) void k_gemm(
    const unsigned short* __restrict__ xpad,
    const unsigned short* __restrict__ kTg,
    const float* __restrict__ bias,
    unsigned short* __restrict__ gates)
{
    __shared__ char smem[131072];

    const int tid  = threadIdx.x;
    const int wid  = tid >> 6;
    const int lane = tid & 63;
    const int wr   = wid >> 2;          // 0..1  (M dir)
    const int wc   = wid & 3;           // 0..3  (N dir)
    const int lrow = lane & 15;
    const int quad = lane >> 4;

    // XCD-aware block mapping: 768 blocks, 8 XCDs, 96 per XCD = 16 mt x 6 nt
    const int bid = blockIdx.x;
    const int wg  = (bid & 7) * 96 + (bid >> 3);
    const int mt  = wg / 6;
    const int nt  = wg % 6;
    const int m0  = mt * 256;
    const int n0  = nt * 256;
    const int boff = m0 >> 12;                  // batch index (4096%256==0: tile in one batch)
    const size_t abase = (size_t)(m0 + boff) * 512;

    // ---- staging decode: linear LDS dest -> (row, kgroup) global source ----
    const int off0 = (wid * 2 + 0) * 1024 + lane * 16;
    const int off1 = (wid * 2 + 1) * 1024 + lane * 16;
    const int ln0 = off0 >> 7, ln1 = off1 >> 7;
    const int g80 = ((off0 >> 4) & 7) ^ (ln0 & 7);
    const int g81 = ((off1 >> 4) & 7) ^ (ln1 & 7);
    const int offL0 = off0, offL1 = off1;
    const int rowS0 = ln0 * 2 + (g80 >> 2), rowS1 = ln1 * 2 + (g81 >> 2);
    const int kcS0 = (g80 & 3) * 8,         kcS1 = (g81 & 3) * 8;

    // ---- fragment-read bases (per-thread constants) ----
    const int lh  = lrow >> 1;                          // 0..7
    const int g8f = ((lrow & 1) * 4 + quad) ^ lh;       // swizzled group, 0..7
    const int ldsA = (wr * 64 + lh) * 128 + g8f * 16;
    const int ldsB = 32768 + (wc * 32 + lh) * 128 + g8f * 16;

    f32x4 acc[8][4] = {};
    bf16x8 afS0[4], afS1[4], bfS0[4], bfS1[4];

    // ---- prologue ----
    STAGE_A(0, 0, 0); STAGE_B(0, 0, 0); STAGE_A(0, 0, 1); STAGE_B(0, 0, 1);
    VM4;
    __builtin_amdgcn_s_barrier();
    afS0[0] = LDS_A(0, 0, 0); afS0[1] = LDS_A(0, 0, 1);
    afS0[2] = LDS_A(0, 0, 2); afS0[3] = LDS_A(0, 0, 3);
    bfS0[0] = LDS_B(0, 0, 0); bfS0[1] = LDS_B(0, 0, 1);
    bfS0[2] = LDS_B(0, 0, 2); bfS0[3] = LDS_B(0, 0, 3);

    for (int i = 0; i < 7; ++i) {
        const int t1 = 2 * i + 1;
        const int t2 = 2 * i + 2;
        PH(1, 0, 0, 1, afS1, 0, bfS0, afS0, bfS0, 0, STAGE_A(1, t1, 0), VM2)
        PH(1, 0, 1, 0, afS0, 1, bfS1, afS1, bfS0, 1, STAGE_B(1, t1, 0), (void)0)
        PH(1, 0, 1, 1, afS1, 0, bfS0, afS0, bfS1, 0, STAGE_A(1, t1, 1), VM2)
        PH(1, 1, 0, 0, afS0, 1, bfS0, afS1, bfS1, 1, STAGE_B(1, t1, 1), (void)0)
        PH(1, 1, 0, 1, afS1, 0, bfS0, afS0, bfS0, 0, STAGE_A(0, t2, 0), VM2)
        PH(1, 1, 1, 0, afS0, 1, bfS1, afS1, bfS0, 1, STAGE_B(0, t2, 0), (void)0)
        PH(1, 1, 1, 1, afS1, 0, bfS0, afS0, bfS1, 0, STAGE_A(0, t2, 1), VM2)
        PH(1, 0, 0, 0, afS0, 1, bfS0, afS1, bfS1, 1, STAGE_B(0, t2, 1), (void)0)
    }
    {
        PH(1, 0, 0, 1, afS1, 0, bfS0, afS0, bfS0, 0, STAGE_A(1, 15, 0), VM2)
        PH(1, 0, 1, 0, afS0, 1, bfS1, afS1, bfS0, 1, STAGE_B(1, 15, 0), (void)0)
        PH(1, 0, 1, 1, afS1, 0, bfS0, afS0, bfS1, 0, STAGE_A(1, 15, 1), VM2)
        PH(1, 1, 0, 0, afS0, 1, bfS0, afS1, bfS1, 1, STAGE_B(1, 15, 1), (void)0)
        PH(1, 1, 0, 1, afS1, 0, bfS0, afS0, bfS0, 0, (void)0,           VM0)
        PH(1, 1, 1, 0, afS0, 1, bfS1, afS1, bfS0, 1, (void)0,           (void)0)
        PH(1, 1, 1, 1, afS1, 0, bfS0, afS0, bfS1, 0, (void)0,           (void)0)
        PH(0, 0, 0, 0, afS0, 0, bfS0, afS1, bfS1, 1, (void)0,           (void)0)
    }

    // ---- epilogue: bias + LDS-staged coalesced store ----
    __syncthreads();
#pragma unroll
    for (int n = 0; n < 4; ++n) {
        int coll = wc * 64 + n * 16 + lrow;        // local col 0..255
        float bv = bias[n0 + coll];
        int g    = coll >> 3;
        int cb   = (coll & 7) * 2;
#pragma unroll
        for (int m = 0; m < 8; ++m) {
            int rbase = wr * 128 + m * 16 + quad * 4;
#pragma unroll
            for (int r = 0; r < 4; ++r) {
                int row = rbase + r;
                *(unsigned short*)(smem + row * 512 + ((g ^ (row & 7)) * 16) + cb)
                    = f2bf(acc[m][n][r] + bv);
            }
        }
    }
    __syncthreads();
    {
        unsigned short* gbase = gates + (size_t)m0 * NN + n0;
#pragma unroll
        for (int it = 0; it < 16; ++it) {
            int idx = it * 512 + tid;              // 0..8191 (16B chunks)
            int row = idx >> 5;                    // 0..255
            int g   = idx & 31;                    // 16B group within row
            bf16x8 v = *(const bf16x8*)(smem + row * 512 + ((g ^ (row & 7)) * 16));
            *(bf16x8*)(gbase + (size_t)row * NN + g * 8) = v;
        }
    }
}

// ---- 3) fused scan: single kernel, decoupled lookback over 128 chunks/batch ----
// Block (b,chunk): local scan (phase A) -> publish aggregate (F,E) with agent-scope
// atomics + release status=1 -> batch-4 lookback over predecessors (acquire) ->
// publish inclusive + status=2 -> replay chunk (gates re-read is LLC-hot) and emit.
// Deadlock-free: 1024 blocks, <=128 VGPR (launch_bounds(128,4)), 0 LDS ->
// >=8 blocks/CU capacity = 2048 co-resident slots >= 1024 launched (2x margin);
// additionally, dependencies point only to lower blockIdx (in-order dispatch safe).
__global__ __launch_bounds__(128, 4) void k_scan(
    const unsigned short* __restrict__ gates,
    float* AggF, float* AggE, float* Inc, unsigned* status,
    float* __restrict__ out)
{
    const int bid   = blockIdx.x;
    const int chunk = bid & (NCH2 - 1);
    const int b     = bid >> 7;
    const int tid   = threadIdx.x;
    const int u     = tid << 2;                      // 4 units/thread
    const size_t g0 = ((size_t)b * TT + (size_t)chunk * CHL2) * NN + u;
    const size_t ai = ((size_t)b * NCH2 + chunk) * UU + u;
    const int    si = b * NCH2 + chunk;

    // ---------------- phase A: local scan + f-product ----------------
    float c[4]  = {0.f, 0.f, 0.f, 0.f};
    float Fa[4] = {1.f, 1.f, 1.f, 1.f};
    {
        ushort4 bz[4], bf4[4];
#pragma unroll
        for (int j = 0; j < 4; ++j) {
            bz[j]  = *(const ushort4*)(gates + g0 + (size_t)j * NN);
            bf4[j] = *(const ushort4*)(gates + g0 + (size_t)j * NN + UU);
        }
        for (int h = 0; h < 8; ++h) {
            ushort4 nz[4], nf[4];
            if (h < 7) {
#pragma unroll
                for (int j = 0; j < 4; ++j) {
                    size_t gg = g0 + (size_t)((h + 1) * 4 + j) * NN;
                    nz[j] = *(const ushort4*)(gates + gg);
                    nf[j] = *(const ushort4*)(gates + gg + UU);
                }
            }
#pragma unroll
            for (int j = 0; j < 4; ++j) {
                float f0 = sigf(bf2f(bf4[j].x)), z0 = tanh_(bf2f(bz[j].x));
                float f1 = sigf(bf2f(bf4[j].y)), z1 = tanh_(bf2f(bz[j].y));
                float f2 = sigf(bf2f(bf4[j].z)), z2 = tanh_(bf2f(bz[j].z));
                float f3 = sigf(bf2f(bf4[j].w)), z3 = tanh_(bf2f(bz[j].w));
                c[0] = f0 * c[0] + (1.0f - f0) * z0; Fa[0] *= f0;
                c[1] = f1 * c[1] + (1.0f - f1) * z1; Fa[1] *= f1;
                c[2] = f2 * c[2] + (1.0f - f2) * z2; Fa[2] *= f2;
                c[3] = f3 * c[3] + (1.0f - f3) * z3; Fa[3] *= f3;
            }
            if (h < 7) {
#pragma unroll
                for (int j = 0; j < 4; ++j) { bz[j] = nz[j]; bf4[j] = nf[j]; }
            }
        }
    }
    // publish aggregate (relaxed agent atomics), then release status=1
#pragma unroll
    for (int e = 0; e < 4; ++e) {
        __hip_atomic_store(AggF + ai + e, Fa[e], __ATOMIC_RELAXED, __HIP_MEMORY_SCOPE_AGENT);
        __hip_atomic_store(AggE + ai + e, c[e],  __ATOMIC_RELAXED, __HIP_MEMORY_SCOPE_AGENT);
    }
    __threadfence();
    __syncthreads();
    if (tid == 0)
        __hip_atomic_store(status + si, 1u, __ATOMIC_RELEASE, __HIP_MEMORY_SCOPE_AGENT);

    // ---------------- lookback: carry_in for this chunk ----------------
    float carry[4] = {0.f, 0.f, 0.f, 0.f};
    if (chunk > 0) {
        float runF[4] = {1.f, 1.f, 1.f, 1.f};
        int k = chunk - 1;
        for (;;) {
            if (k < 0) break;                         // reached start: carry complete
            int nb = (k >= 3) ? 4 : (k + 1);
            unsigned st[4];
            float Fv[4][4], Ev[4][4], Iv[4][4];
#pragma unroll
            for (int j = 0; j < 4; ++j) {
                if (j < nb)
                    st[j] = __hip_atomic_load(status + b * NCH2 + (k - j),
                                              __ATOMIC_ACQUIRE, __HIP_MEMORY_SCOPE_AGENT);
            }
#pragma unroll
            for (int j = 0; j < 4; ++j) {
                if (j < nb) {
                    size_t aj = ((size_t)b * NCH2 + (k - j)) * UU + u;
#pragma unroll
                    for (int e = 0; e < 4; ++e) {
                        Fv[j][e] = __hip_atomic_load(AggF + aj + e, __ATOMIC_RELAXED, __HIP_MEMORY_SCOPE_AGENT);
                        Ev[j][e] = __hip_atomic_load(AggE + aj + e, __ATOMIC_RELAXED, __HIP_MEMORY_SCOPE_AGENT);
                        Iv[j][e] = __hip_atomic_load(Inc  + aj + e, __ATOMIC_RELAXED, __HIP_MEMORY_SCOPE_AGENT);
                    }
                }
            }
            bool done = false;
            int adv = nb;
            for (int j = 0; j < nb; ++j) {
                if (st[j] == 0u) { adv = j; break; }  // consumed j entries; retry
                if (st[j] == 2u) {                    // inclusive: finish
#pragma unroll
                    for (int e = 0; e < 4; ++e) carry[e] = fmaf(runF[e], Iv[j][e], carry[e]);
                    done = true; break;
                }
                // aggregate
#pragma unroll
                for (int e = 0; e < 4; ++e) {
                    carry[e] = fmaf(runF[e], Ev[j][e], carry[e]);
                    runF[e] *= Fv[j][e];
                }
            }
            if (done) break;
            k -= adv;
            if (adv == 0) __builtin_amdgcn_s_sleep(2);
        }
    }
    // publish inclusive = F*carry + E, then release status=2
#pragma unroll
    for (int e = 0; e < 4; ++e) {
        float inc = fmaf(Fa[e], carry[e], c[e]);
        __hip_atomic_store(Inc + ai + e, inc, __ATOMIC_RELAXED, __HIP_MEMORY_SCOPE_AGENT);
    }
    __threadfence();
    __syncthreads();
    if (tid == 0)
        __hip_atomic_store(status + si, 2u, __ATOMIC_RELEASE, __HIP_MEMORY_SCOPE_AGENT);

    // ---------------- replay with true carry; emit out = o * c ----------------
    {
        float c0 = carry[0], c1 = carry[1], c2 = carry[2], c3 = carry[3];
        size_t o = ((size_t)b * TT + (size_t)chunk * CHL2) * UU + u;
        ushort4 bz[4], bf4[4], bo[4];
#pragma unroll
        for (int j = 0; j < 4; ++j) {
            bz[j]  = *(const ushort4*)(gates + g0 + (size_t)j * NN);
            bf4[j] = *(const ushort4*)(gates + g0 + (size_t)j * NN + UU);
            bo[j]  = *(const ushort4*)(gates + g0 + (size_t)j * NN + 2 * UU);
        }
        for (int h = 0; h < 8; ++h) {
            ushort4 nz[4], nf[4], no[4];
            if (h < 7) {
#pragma unroll
                for (int j = 0; j < 4; ++j) {
                    size_t gg = g0 + (size_t)((h + 1) * 4 + j) * NN;
                    nz[j] = *(const ushort4*)(gates + gg);
                    nf[j] = *(const ushort4*)(gates + gg + UU);
                    no[j] = *(const ushort4*)(gates + gg + 2 * UU);
                }
            }
#pragma unroll
            for (int j = 0; j < 4; ++j) {
                float f0 = sigf(bf2f(bf4[j].x)), z0 = tanh_(bf2f(bz[j].x)), o0 = sigf(bf2f(bo[j].x));
                float f1 = sigf(bf2f(bf4[j].y)), z1 = tanh_(bf2f(bz[j].y)), o1 = sigf(bf2f(bo[j].y));
                float f2 = sigf(bf2f(bf4[j].z)), z2 = tanh_(bf2f(bz[j].z)), o2 = sigf(bf2f(bo[j].z));
                float f3 = sigf(bf2f(bf4[j].w)), z3 = tanh_(bf2f(bz[j].w)), o3 = sigf(bf2f(bo[j].w));
                c0 = f0 * c0 + (1.0f - f0) * z0;
                c1 = f1 * c1 + (1.0f - f1) * z1;
                c2 = f2 * c2 + (1.0f - f2) * z2;
                c3 = f3 * c3 + (1.0f - f3) * z3;
                f32x4 ov = { o0 * c0, o1 * c1, o2 * c2, o3 * c3 };
                __builtin_nontemporal_store(ov, (f32x4*)(out + o));
                o += UU;
            }
            if (h < 7) {
#pragma unroll
                for (int j = 0; j < 4; ++j) { bz[j] = nz[j]; bf4[j] = nf[j]; bo[j] = no[j]; }
            }
        }
    }
}

extern "C" void kernel_launch(void* const* d_in, const int* in_sizes, int n_in,
                              void* d_out, int out_size, void* d_ws, size_t ws_size,
                              hipStream_t stream) {
    const float* x    = (const float*)d_in[0];
    const float* kern = (const float*)d_in[1];
    const float* bias = (const float*)d_in[2];
    float* out = (float*)d_out;
    char* ws = (char*)d_ws;

    // workspace layout (bytes)
    unsigned short* xpad  = (unsigned short*)(ws + 0);           // 8*4097*512*2   = 33,562,624
    unsigned short* kT    = (unsigned short*)(ws + 33562624);    // 1536*1024*2    =  3,145,728
    unsigned short* gates = (unsigned short*)(ws + 36708352);    // 32768*1536*2   = 100,663,296
    float* AggF = (float*)(ws + 137371648);                      // 8*128*512*4    =  2,097,152 (in Fp slot)
    float* AggE = (float*)(ws + 141565952);                      // (in Ce slot)
    float* Inc  = (float*)(ws + 145760256);                      // (in Cin slot)
    // status: aliases the dead kT region (kT consumed by k_gemm before memset below)
    unsigned* status = (unsigned*)(ws + 33562624);               // 8*128*4 = 4096 B

    hipLaunchKernelGGL(k_prep,  dim3(2049 + 24, 8), dim3(256), 0, stream, x, xpad, kern, kT);
    hipLaunchKernelGGL(k_gemm,  dim3(768),          dim3(512), 0, stream, xpad, kT, bias, gates);
    hipMemsetAsync(status, 0, BB * NCH2 * sizeof(unsigned), stream);
    hipLaunchKernelGGL(k_scan,  dim3(NCH2 * BB),    dim3(128), 0, stream,
                       gates, AggF, AggE, Inc, status, out);
}

// Round 10
// 309.742 us; speedup vs baseline: 2.6387x; 2.6387x over previous
//
#include <hip/hip_runtime.h>
#include <cstdint>
#include <cstddef>

// Problem constants
#define BB   8
#define TT   4096
#define DD   512
#define UU   512
#define NN   1536   // 3*UU
#define KK   1024   // 2*DD
#define MM   32768  // BB*TT
#define NCH  256    // number of scan chunks
#define CHL  16     // chunk length (NCH*CHL == TT)

using bf16x8 = __attribute__((ext_vector_type(8))) __bf16;
using f32x4  = __attribute__((ext_vector_type(4))) float;

__device__ __forceinline__ unsigned short f2bf(float f) {
    unsigned u = __float_as_uint(f);
    u += 0x7fffu + ((u >> 16) & 1u);   // RTNE
    return (unsigned short)(u >> 16);
}
__device__ __forceinline__ float bf2f(unsigned short s) {
    return __uint_as_float(((unsigned)s) << 16);
}
__device__ __forceinline__ float sigf(float x) { return 1.0f / (1.0f + __expf(-x)); }
__device__ __forceinline__ float tanh_(float x) { return 1.0f - 2.0f / (1.0f + __expf(2.0f * x)); }

__device__ __forceinline__ void async16(const void* g, void* l) {
    __builtin_amdgcn_global_load_lds(
        (__attribute__((address_space(1))) void*)g,
        (__attribute__((address_space(3))) void*)l, 16, 0, 0);
}

// ---- 1) prep: pad+convert x -> xpad (bf16), and transpose kernel -> kT ----
__global__ void k_prep(const float* __restrict__ x, unsigned short* __restrict__ xpad,
                       const float* __restrict__ kern, unsigned short* __restrict__ kT) {
    int bx = blockIdx.x;
    int by = blockIdx.y;
    int tid = threadIdx.x;
    if (bx < 2049) {
        int q = bx * 256 + tid;              // quad index within batch
        if (q >= 4097 * 128) return;
        int tp = q >> 7;                     // 0..4096
        int d  = (q & 127) << 2;             // 0..508
        size_t oi = ((size_t)by * 4097 + tp) * 512 + d;
        ushort4 o;
        if (tp == 0) {
            o.x = o.y = o.z = o.w = 0;
        } else {
            float4 v = *(const float4*)(x + ((size_t)by * 4096 + (tp - 1)) * 512 + d);
            o.x = f2bf(v.x); o.y = f2bf(v.y); o.z = f2bf(v.z); o.w = f2bf(v.w);
        }
        *(ushort4*)(xpad + oi) = o;
    } else {
        __shared__ float tile[32][33];
        int idx = (bx - 2049) * 8 + by;      // 0..191
        int c  = tid & 31;
        int r0 = tid >> 5;                   // 0..7
        for (int t8 = 0; t8 < 8; ++t8) {
            int tnum = idx * 8 + t8;         // 0..1535
            int k0 = (tnum & 31) * 32;       // 32 K-tiles
            int n0 = (tnum >> 5) * 32;       // 48 N-tiles
#pragma unroll
            for (int rr = r0; rr < 32; rr += 8)
                tile[rr][c] = kern[(size_t)(k0 + rr) * NN + n0 + c];
            __syncthreads();
#pragma unroll
            for (int rr = r0; rr < 32; rr += 8)
                kT[(size_t)(n0 + rr) * KK + k0 + c] = f2bf(tile[c][rr]);
            __syncthreads();
        }
    }
}

// ---- 2) GEMM: 256x256 tile, BK=64, 8 waves (2Mx4N), 8-phase READ-AHEAD pipeline ----
// Phase p: [bar] [ds_read frags for p+1 into alternate reg set] [stage] [sched_barrier]
//          [MFMA(p) from regs read during p-1] [counted vmcnt at even-phase ends].

#define STAGE_A(BUF, KT, KH) do { \
    async16(xpad + abase + (size_t)rowS0 * 512 + ((KT) * 64 + (KH) * 32 + kcS0), \
            smem + (BUF) * 65536 + (KH) * 16384 + offL0); \
    async16(xpad + abase + (size_t)rowS1 * 512 + ((KT) * 64 + (KH) * 32 + kcS1), \
            smem + (BUF) * 65536 + (KH) * 16384 + offL1); \
} while (0)

#define STAGE_B(BUF, KT, KH) do { \
    async16(kTg + (size_t)(n0 + rowS0) * 1024 + ((KT) * 64 + (KH) * 32 + kcS0), \
            smem + (BUF) * 65536 + 32768 + (KH) * 16384 + offL0); \
    async16(kTg + (size_t)(n0 + rowS1) * 1024 + ((KT) * 64 + (KH) * 32 + kcS1), \
            smem + (BUF) * 65536 + 32768 + (KH) * 16384 + offL1); \
} while (0)

#define VM4 asm volatile("s_waitcnt vmcnt(4)" ::: "memory")
#define VM2 asm volatile("s_waitcnt vmcnt(2)" ::: "memory")
#define VM0 asm volatile("s_waitcnt vmcnt(0)" ::: "memory")

#define LDS_A(BUF, KS, MR) (*(const bf16x8*)(smem + (BUF) * 65536 + (KS) * 16384 + (MR) * 1024 + ldsA))
#define LDS_B(BUF, KS, NR) (*(const bf16x8*)(smem + (BUF) * 65536 + (KS) * 16384 + (NR) * 1024 + ldsB))

#define PH(DO_R, RBUF, RKS, RMH, AFN, LBN, BFN, AFC, BFC, MH, STG, VMW) \
    __builtin_amdgcn_s_barrier(); \
    if (DO_R) { \
        AFN[0] = LDS_A(RBUF, RKS, (RMH) * 4 + 0); \
        AFN[1] = LDS_A(RBUF, RKS, (RMH) * 4 + 1); \
        AFN[2] = LDS_A(RBUF, RKS, (RMH) * 4 + 2); \
        AFN[3] = LDS_A(RBUF, RKS, (RMH) * 4 + 3); \
        if (LBN) { \
            BFN[0] = LDS_B(RBUF, RKS, 0); \
            BFN[1] = LDS_B(RBUF, RKS, 1); \
            BFN[2] = LDS_B(RBUF, RKS, 2); \
            BFN[3] = LDS_B(RBUF, RKS, 3); \
        } \
    } \
    STG; \
    __builtin_amdgcn_sched_barrier(0); \
    __builtin_amdgcn_s_setprio(1); \
    acc[(MH)*4+0][0] = __builtin_amdgcn_mfma_f32_16x16x32_bf16(AFC[0], BFC[0], acc[(MH)*4+0][0], 0, 0, 0); \
    acc[(MH)*4+0][1] = __builtin_amdgcn_mfma_f32_16x16x32_bf16(AFC[0], BFC[1], acc[(MH)*4+0][1], 0, 0, 0); \
    acc[(MH)*4+0][2] = __builtin_amdgcn_mfma_f32_16x16x32_bf16(AFC[0], BFC[2], acc[(MH)*4+0][2], 0, 0, 0); \
    acc[(MH)*4+0][3] = __builtin_amdgcn_mfma_f32_16x16x32_bf16(AFC[0], BFC[3], acc[(MH)*4+0][3], 0, 0, 0); \
    acc[(MH)*4+1][0] = __builtin_amdgcn_mfma_f32_16x16x32_bf16(AFC[1], BFC[0], acc[(MH)*4+1][0], 0, 0, 0); \
    acc[(MH)*4+1][1] = __builtin_amdgcn_mfma_f32_16x16x32_bf16(AFC[1], BFC[1], acc[(MH)*4+1][1], 0, 0, 0); \
    acc[(MH)*4+1][2] = __builtin_amdgcn_mfma_f32_16x16x32_bf16(AFC[1], BFC[2], acc[(MH)*4+1][2], 0, 0, 0); \
    acc[(MH)*4+1][3] = __builtin_amdgcn_mfma_f32_16x16x32_bf16(AFC[1], BFC[3], acc[(MH)*4+1][3], 0, 0, 0); \
    acc[(MH)*4+2][0] = __builtin_amdgcn_mfma_f32_16x16x32_bf16(AFC[2], BFC[0], acc[(MH)*4+2][0], 0, 0, 0); \
    acc[(MH)*4+2][1] = __builtin_amdgcn_mfma_f32_16x16x32_bf16(AFC[2], BFC[1], acc[(MH)*4+2][1], 0, 0, 0); \
    acc[(MH)*4+2][2] = __builtin_amdgcn_mfma_f32_16x16x32_bf16(AFC[2], BFC[2], acc[(MH)*4+2][2], 0, 0, 0); \
    acc[(MH)*4+2][3] = __builtin_amdgcn_mfma_f32_16x16x32_bf16(AFC[2], BFC[3], acc[(MH)*4+2][3], 0, 0, 0); \
    acc[(MH)*4+3][0] = __builtin_amdgcn_mfma_f32_16x16x32_bf16(AFC[3], BFC[0], acc[(MH)*4+3][0], 0, 0, 0); \
    acc[(MH)*4+3][1] = __builtin_amdgcn_mfma_f32_16x16x32_bf16(AFC[3], BFC[1], acc[(MH)*4+3][1], 0, 0, 0); \
    acc[(MH)*4+3][2] = __builtin_amdgcn_mfma_f32_16x16x32_bf16(AFC[3], BFC[2], acc[(MH)*4+3][2], 0, 0, 0); \
    acc[(MH)*4+3][3] = __builtin_amdgcn_mfma_f32_16x16x32_bf16(AFC[3], BFC[3], acc[(MH)*4+3][3], 0, 0, 0); \
    __builtin_amdgcn_s_setprio(0); \
    VMW;

__global__ __launch_bounds__(512, 2) void k_gemm(
    const unsigned short* __restrict__ xpad,
    const unsigned short* __restrict__ kTg,
    const float* __restrict__ bias,
    unsigned short* __restrict__ gates)
{
    __shared__ char smem[131072];

    const int tid  = threadIdx.x;
    const int wid  = tid >> 6;
    const int lane = tid & 63;
    const int wr   = wid >> 2;          // 0..1  (M dir)
    const int wc   = wid & 3;           // 0..3  (N dir)
    const int lrow = lane & 15;
    const int quad = lane >> 4;

    // XCD-aware block mapping: 768 blocks, 8 XCDs, 96 per XCD = 16 mt x 6 nt
    const int bid = blockIdx.x;
    const int wg  = (bid & 7) * 96 + (bid >> 3);
    const int mt  = wg / 6;
    const int nt  = wg % 6;
    const int m0  = mt * 256;
    const int n0  = nt * 256;
    const int boff = m0 >> 12;                  // batch index (4096%256==0: tile in one batch)
    const size_t abase = (size_t)(m0 + boff) * 512;

    // ---- staging decode: linear LDS dest -> (row, kgroup) global source ----
    const int off0 = (wid * 2 + 0) * 1024 + lane * 16;
    const int off1 = (wid * 2 + 1) * 1024 + lane * 16;
    const int ln0 = off0 >> 7, ln1 = off1 >> 7;
    const int g80 = ((off0 >> 4) & 7) ^ (ln0 & 7);
    const int g81 = ((off1 >> 4) & 7) ^ (ln1 & 7);
    const int offL0 = off0, offL1 = off1;
    const int rowS0 = ln0 * 2 + (g80 >> 2), rowS1 = ln1 * 2 + (g81 >> 2);
    const int kcS0 = (g80 & 3) * 8,         kcS1 = (g81 & 3) * 8;

    // ---- fragment-read bases (per-thread constants) ----
    const int lh  = lrow >> 1;                          // 0..7
    const int g8f = ((lrow & 1) * 4 + quad) ^ lh;       // swizzled group, 0..7
    const int ldsA = (wr * 64 + lh) * 128 + g8f * 16;
    const int ldsB = 32768 + (wc * 32 + lh) * 128 + g8f * 16;

    f32x4 acc[8][4] = {};
    bf16x8 afS0[4], afS1[4], bfS0[4], bfS1[4];

    // ---- prologue: stage K-tile 0 into buf0; wait kh0; preload phase-0 fragments ----
    STAGE_A(0, 0, 0); STAGE_B(0, 0, 0); STAGE_A(0, 0, 1); STAGE_B(0, 0, 1);
    VM4;
    __builtin_amdgcn_s_barrier();
    afS0[0] = LDS_A(0, 0, 0); afS0[1] = LDS_A(0, 0, 1);
    afS0[2] = LDS_A(0, 0, 2); afS0[3] = LDS_A(0, 0, 3);
    bfS0[0] = LDS_B(0, 0, 0); bfS0[1] = LDS_B(0, 0, 1);
    bfS0[2] = LDS_B(0, 0, 2); bfS0[3] = LDS_B(0, 0, 3);

    for (int i = 0; i < 7; ++i) {
        const int t1 = 2 * i + 1;
        const int t2 = 2 * i + 2;
        PH(1, 0, 0, 1, afS1, 0, bfS0, afS0, bfS0, 0, STAGE_A(1, t1, 0), VM2)
        PH(1, 0, 1, 0, afS0, 1, bfS1, afS1, bfS0, 1, STAGE_B(1, t1, 0), (void)0)
        PH(1, 0, 1, 1, afS1, 0, bfS0, afS0, bfS1, 0, STAGE_A(1, t1, 1), VM2)
        PH(1, 1, 0, 0, afS0, 1, bfS0, afS1, bfS1, 1, STAGE_B(1, t1, 1), (void)0)
        PH(1, 1, 0, 1, afS1, 0, bfS0, afS0, bfS0, 0, STAGE_A(0, t2, 0), VM2)
        PH(1, 1, 1, 0, afS0, 1, bfS1, afS1, bfS0, 1, STAGE_B(0, t2, 0), (void)0)
        PH(1, 1, 1, 1, afS1, 0, bfS0, afS0, bfS1, 0, STAGE_A(0, t2, 1), VM2)
        PH(1, 0, 0, 0, afS0, 1, bfS0, afS1, bfS1, 1, STAGE_B(0, t2, 1), (void)0)
    }
    {
        PH(1, 0, 0, 1, afS1, 0, bfS0, afS0, bfS0, 0, STAGE_A(1, 15, 0), VM2)
        PH(1, 0, 1, 0, afS0, 1, bfS1, afS1, bfS0, 1, STAGE_B(1, 15, 0), (void)0)
        PH(1, 0, 1, 1, afS1, 0, bfS0, afS0, bfS1, 0, STAGE_A(1, 15, 1), VM2)
        PH(1, 1, 0, 0, afS0, 1, bfS0, afS1, bfS1, 1, STAGE_B(1, 15, 1), (void)0)
        PH(1, 1, 0, 1, afS1, 0, bfS0, afS0, bfS0, 0, (void)0,           VM0)
        PH(1, 1, 1, 0, afS0, 1, bfS1, afS1, bfS0, 1, (void)0,           (void)0)
        PH(1, 1, 1, 1, afS1, 0, bfS0, afS0, bfS1, 0, (void)0,           (void)0)
        PH(0, 0, 0, 0, afS0, 0, bfS0, afS1, bfS1, 1, (void)0,           (void)0)
    }

    // ---- epilogue: bias + LDS-staged coalesced store ----
    __syncthreads();
#pragma unroll
    for (int n = 0; n < 4; ++n) {
        int coll = wc * 64 + n * 16 + lrow;        // local col 0..255
        float bv = bias[n0 + coll];
        int g    = coll >> 3;
        int cb   = (coll & 7) * 2;
#pragma unroll
        for (int m = 0; m < 8; ++m) {
            int rbase = wr * 128 + m * 16 + quad * 4;
#pragma unroll
            for (int r = 0; r < 4; ++r) {
                int row = rbase + r;
                *(unsigned short*)(smem + row * 512 + ((g ^ (row & 7)) * 16) + cb)
                    = f2bf(acc[m][n][r] + bv);
            }
        }
    }
    __syncthreads();
    {
        unsigned short* gbase = gates + (size_t)m0 * NN + n0;
#pragma unroll
        for (int it = 0; it < 16; ++it) {
            int idx = it * 512 + tid;              // 0..8191 (16B chunks)
            int row = idx >> 5;                    // 0..255
            int g   = idx & 31;                    // 16B group within row
            bf16x8 v = *(const bf16x8*)(smem + row * 512 + ((g ^ (row & 7)) * 16));
            *(bf16x8*)(gbase + (size_t)row * NN + g * 8) = v;
        }
    }
}

// ---- 3) pass A: per-chunk local scan + running f-product (batched loads) ----
__global__ __launch_bounds__(128) void k_scanA(const unsigned short* __restrict__ gates,
                        float* __restrict__ Fp, float* __restrict__ Ce) {
    const int chunk = blockIdx.x;        // 0..255
    const int b     = blockIdx.y;        // 0..7
    const int u     = threadIdx.x << 2;  // 128 threads * 4
    const size_t g0 = ((size_t)b * TT + (size_t)chunk * CHL) * NN + u;

    float c0 = 0, c1 = 0, c2 = 0, c3 = 0;
    float F0 = 1, F1 = 1, F2 = 1, F3 = 1;

    ushort4 bz[8], bf_[8];
#pragma unroll
    for (int j = 0; j < 8; ++j) {
        bz[j]  = *(const ushort4*)(gates + g0 + (size_t)j * NN);
        bf_[j] = *(const ushort4*)(gates + g0 + (size_t)j * NN + UU);
    }
#pragma unroll
    for (int h = 0; h < 2; ++h) {
        ushort4 nz[8], nf[8];
        if (h == 0) {
#pragma unroll
            for (int j = 0; j < 8; ++j) {
                nz[j] = *(const ushort4*)(gates + g0 + (size_t)(8 + j) * NN);
                nf[j] = *(const ushort4*)(gates + g0 + (size_t)(8 + j) * NN + UU);
            }
        }
#pragma unroll
        for (int j = 0; j < 8; ++j) {
            float f0 = sigf(bf2f(bf_[j].x)), z0 = tanh_(bf2f(bz[j].x));
            float f1 = sigf(bf2f(bf_[j].y)), z1 = tanh_(bf2f(bz[j].y));
            float f2 = sigf(bf2f(bf_[j].z)), z2 = tanh_(bf2f(bz[j].z));
            float f3 = sigf(bf2f(bf_[j].w)), z3 = tanh_(bf2f(bz[j].w));
            c0 = f0 * c0 + (1.0f - f0) * z0; F0 *= f0;
            c1 = f1 * c1 + (1.0f - f1) * z1; F1 *= f1;
            c2 = f2 * c2 + (1.0f - f2) * z2; F2 *= f2;
            c3 = f3 * c3 + (1.0f - f3) * z3; F3 *= f3;
        }
        if (h == 0) {
#pragma unroll
            for (int j = 0; j < 8; ++j) { bz[j] = nz[j]; bf_[j] = nf[j]; }
        }
    }
    size_t ci = ((size_t)b * NCH + chunk) * UU + u;
    *(float4*)(Fp + ci) = make_float4(F0, F1, F2, F3);
    *(float4*)(Ce + ci) = make_float4(c0, c1, c2, c3);
}

// ---- 4) pass B: sequential scan over chunks -> carry-in per chunk ----
__global__ __launch_bounds__(128) void k_scanB(const float* __restrict__ Fp,
                        const float* __restrict__ Ce, float* __restrict__ Cin) {
    int gid = blockIdx.x * 128 + threadIdx.x;   // 0..4095
    int bb = gid >> 9;           // batch
    int uu = gid & 511;          // unit
    size_t base = (size_t)bb * NCH * UU + uu;
    float c = 0.0f;
    for (int k0 = 0; k0 < NCH; k0 += 8) {
        float F[8], E[8];
#pragma unroll
        for (int j = 0; j < 8; ++j) {
            F[j] = Fp[base + (size_t)(k0 + j) * UU];
            E[j] = Ce[base + (size_t)(k0 + j) * UU];
        }
#pragma unroll
        for (int j = 0; j < 8; ++j) {
            Cin[base + (size_t)(k0 + j) * UU] = c;
            c = F[j] * c + E[j];
        }
    }
}

// ---- 5) pass C: replay chunk with true carry, emit out = o * c ----
__global__ __launch_bounds__(128) void k_scanC(const unsigned short* __restrict__ gates,
                        const float* __restrict__ Cin, float* __restrict__ out) {
    const int chunk = blockIdx.x;
    const int b     = blockIdx.y;
    const int u     = threadIdx.x << 2;
    const size_t g0 = ((size_t)b * TT + (size_t)chunk * CHL) * NN + u;
    size_t o = ((size_t)b * TT + (size_t)chunk * CHL) * UU + u;

    size_t ci = ((size_t)b * NCH + chunk) * UU + u;
    float4 cv = *(const float4*)(Cin + ci);
    float c0 = cv.x, c1 = cv.y, c2 = cv.z, c3 = cv.w;

    ushort4 bz[4], bf_[4], bo[4];
#pragma unroll
    for (int j = 0; j < 4; ++j) {
        bz[j]  = *(const ushort4*)(gates + g0 + (size_t)j * NN);
        bf_[j] = *(const ushort4*)(gates + g0 + (size_t)j * NN + UU);
        bo[j]  = *(const ushort4*)(gates + g0 + (size_t)j * NN + 2 * UU);
    }
#pragma unroll
    for (int k = 0; k < 4; ++k) {
        ushort4 nz[4], nf[4], no[4];
        if (k < 3) {
#pragma unroll
            for (int j = 0; j < 4; ++j) {
                size_t gg = g0 + (size_t)((k + 1) * 4 + j) * NN;
                nz[j] = *(const ushort4*)(gates + gg);
                nf[j] = *(const ushort4*)(gates + gg + UU);
                no[j] = *(const ushort4*)(gates + gg + 2 * UU);
            }
        }
#pragma unroll
        for (int j = 0; j < 4; ++j) {
            float f0 = sigf(bf2f(bf_[j].x)), z0 = tanh_(bf2f(bz[j].x)), o0 = sigf(bf2f(bo[j].x));
            float f1 = sigf(bf2f(bf_[j].y)), z1 = tanh_(bf2f(bz[j].y)), o1 = sigf(bf2f(bo[j].y));
            float f2 = sigf(bf2f(bf_[j].z)), z2 = tanh_(bf2f(bz[j].z)), o2 = sigf(bf2f(bo[j].z));
            float f3 = sigf(bf2f(bf_[j].w)), z3 = tanh_(bf2f(bz[j].w)), o3 = sigf(bf2f(bo[j].w));
            c0 = f0 * c0 + (1.0f - f0) * z0;
            c1 = f1 * c1 + (1.0f - f1) * z1;
            c2 = f2 * c2 + (1.0f - f2) * z2;
            c3 = f3 * c3 + (1.0f - f3) * z3;
            f32x4 ov = { o0 * c0, o1 * c1, o2 * c2, o3 * c3 };
            __builtin_nontemporal_store(ov, (f32x4*)(out + o));
            o += UU;
        }
        if (k < 3) {
#pragma unroll
            for (int j = 0; j < 4; ++j) { bz[j] = nz[j]; bf_[j] = nf[j]; bo[j] = no[j]; }
        }
    }
}

extern "C" void kernel_launch(void* const* d_in, const int* in_sizes, int n_in,
                              void* d_out, int out_size, void* d_ws, size_t ws_size,
                              hipStream_t stream) {
    const float* x    = (const float*)d_in[0];
    const float* kern = (const float*)d_in[1];
    const float* bias = (const float*)d_in[2];
    float* out = (float*)d_out;
    char* ws = (char*)d_ws;

    // workspace layout (bytes)
    unsigned short* xpad  = (unsigned short*)(ws + 0);           // 8*4097*512*2   = 33,562,624
    unsigned short* kT    = (unsigned short*)(ws + 33562624);    // 1536*1024*2    =  3,145,728
    unsigned short* gates = (unsigned short*)(ws + 36708352);    // 32768*1536*2   = 100,663,296
    float* Fp  = (float*)(ws + 137371648);                       // 8*256*512*4    =  4,194,304
    float* Ce  = (float*)(ws + 141565952);                       //                =  4,194,304
    float* Cin = (float*)(ws + 145760256);                       //                =  4,194,304
    // total: 149,954,560 bytes

    hipLaunchKernelGGL(k_prep,  dim3(2049 + 24, 8), dim3(256), 0, stream, x, xpad, kern, kT);
    hipLaunchKernelGGL(k_gemm,  dim3(768),          dim3(512), 0, stream, xpad, kT, bias, gates);
    hipLaunchKernelGGL(k_scanA, dim3(NCH, BB),      dim3(128), 0, stream, gates, Fp, Ce);
    hipLaunchKernelGGL(k_scanB, dim3(32),           dim3(128), 0, stream, Fp, Ce, Cin);
    hipLaunchKernelGGL(k_scanC, dim3(NCH, BB),      dim3(128), 0, stream, gates, Cin, out);
}